// Round 18
// baseline (740.959 us; speedup 1.0000x reference)
//
#include <hip/hip_runtime.h>
#include <math.h>

// ---------------- problem constants ----------------
constexpr int NB = 4;            // batch
constexpr int NC = 512;          // channels
constexpr int NH = 64, NW = 64;  // spatial
constexpr int NPOS = NH * NW;        // 4096
constexpr int NANCH = NPOS * 9;      // 36864 anchors/batch
constexpr int PRE_TOPN = 6000;
constexpr int POST_TOPN = 300;
constexpr int CAND_CAP = 40960;

typedef short short8_t __attribute__((ext_vector_type(8)));
typedef float f32x4_t __attribute__((ext_vector_type(4)));

constexpr size_t IPLANE = (size_t)NB * NPOS * 512;   // shorts per input plane

// anchors for base_size=16, ratios {0.5,1,2}, scales {8,16,32} (verified vs numpy)
__device__ __constant__ float A9c[9][4] = {
  {-84.f,-40.f,99.f,55.f},   {-176.f,-88.f,191.f,103.f}, {-360.f,-184.f,375.f,199.f},
  {-56.f,-56.f,71.f,71.f},   {-120.f,-120.f,135.f,135.f},{-248.f,-248.f,263.f,263.f},
  {-36.f,-80.f,51.f,95.f},   {-80.f,-168.f,95.f,183.f},  {-168.f,-344.f,183.f,359.f}};

// ---------------- ws layout (bytes) ----------------
constexpr size_t OFF_WB   = 0;          // 9*3*512*512*2  = 14,155,776 (bf16 W planes; dead after conv)
constexpr size_t OFF_IB   = 14155776;   // 3*4*4096*512*2 = 50,331,648 (bf16 input planes; dead after conv)
constexpr size_t OFF_CONV = 64487424;   // 4*512*4096*4   = 33,554,432
constexpr size_t OFF_HIST = 98041856;   // 65,536
constexpr size_t OFF_MISC = 98107392;   // 256
// overlays (written only after their host region is dead):
constexpr size_t OFF_HEAD = 0;          // 3,538,944 (inside WB, after conv)
constexpr size_t OFF_SKEY = 3538944;    // 589,824
constexpr size_t OFF_BOX  = 4128768;    // 2,359,296
constexpr size_t OFF_CKEY = 6488064;    // 655,360
constexpr size_t OFF_CIDX = 7143424;    // 655,360
constexpr size_t OFF_SBOX = 7798784;    // 384,000 -> end 8,182,784 < 14,155,776 OK
// total ws = 98,107,648 bytes

// ---------------- bf16 helpers (RNE) ----------------
__device__ inline unsigned short f2bf(float f) {
  unsigned u = __float_as_uint(f);
  unsigned r = u + 0x7fffu + ((u >> 16) & 1u);
  return (unsigned short)(r >> 16);
}
__device__ inline float bf2f(unsigned short h) { return __uint_as_float(((unsigned)h) << 16); }

// split 8 floats into hi/mid/lo bf16 (24 mantissa bits total)
__device__ inline void split8(const float4 A, const float4 B, short8_t& h, short8_t& m, short8_t& l) {
#define SPL(J, X) { unsigned short hh = f2bf(X); float fh = bf2f(hh); \
                    unsigned short mm = f2bf((X) - fh); float fm = bf2f(mm); \
                    unsigned short ll = f2bf((X) - fh - fm); \
                    h[J] = (short)hh; m[J] = (short)mm; l[J] = (short)ll; }
  SPL(0, A.x) SPL(1, A.y) SPL(2, A.z) SPL(3, A.w)
  SPL(4, B.x) SPL(5, B.y) SPL(6, B.z) SPL(7, B.w)
#undef SPL
}

// ---------------- W[ko][c][tap] fp32 -> Wb[tap][plane][ko][c] bf16 (pre-split) --------
__global__ __launch_bounds__(256) void wsplit_k(const float* __restrict__ Wc,
                                               short* __restrict__ Wb) {
  const int i = blockIdx.x * 256 + threadIdx.x;   // exact: 9*512*512 / 256 = 9216 blocks
  const int tap = i >> 18;
  const int ko = (i >> 9) & 511, c = i & 511;
  const float w = Wc[(size_t)ko * 4608 + c * 9 + tap];
  const unsigned short h = f2bf(w);
  const float fh = bf2f(h);
  const unsigned short m = f2bf(w - fh);
  const float fm = bf2f(m);
  const unsigned short l = f2bf(w - fh - fm);
  const size_t base = ((size_t)tap * 3 * 512 + ko) * 512 + c;
  Wb[base] = (short)h;
  Wb[base + 512 * 512] = (short)m;
  Wb[base + 2 * 512 * 512] = (short)l;
}

// ---------------- input [b][c][pos] fp32 -> Ib[plane][b][pos][c] bf16 (pre-split) -----
// Same f2bf chain as the old in-kernel split -> bit-identical plane values (R13-proven).
__global__ __launch_bounds__(256) void cvt_split_k(const float* __restrict__ in,
                                                   short* __restrict__ Ib) {
  __shared__ float T[64][65];
  const int b = blockIdx.z, c0 = blockIdx.y * 64, pos0 = blockIdx.x * 64;
  const int tid = threadIdx.x;
  for (int i = tid; i < 4096; i += 256) {
    int cc = i >> 6, pp = i & 63;
    T[cc][pp] = in[(((size_t)b * 512 + c0 + cc) << 12) + pos0 + pp];
  }
  __syncthreads();
  #pragma unroll
  for (int it = 0; it < 2; ++it) {
    const int i = it * 256 + tid;          // 512 tasks: pp x cpart(8c)
    const int pp = i >> 3, cpart = i & 7;
    float v[8];
    #pragma unroll
    for (int j = 0; j < 8; ++j) v[j] = T[cpart * 8 + j][pp];
    short8_t h, m, l;
    split8(make_float4(v[0], v[1], v[2], v[3]), make_float4(v[4], v[5], v[6], v[7]), h, m, l);
    const size_t dst = ((((size_t)b << 12) + pos0 + pp) << 9) + c0 + (cpart << 3);
    *(short8_t*)(Ib + dst) = h;
    *(short8_t*)(Ib + IPLANE + dst) = m;
    *(short8_t*)(Ib + 2 * IPLANE + dst) = l;
  }
}

// ---------------- conv3x3 + bias + relu via MFMA (bf16x3, all-pre-split) --------------
// R17 structure (weight prefetch kept) with input staging as raw 16B plane copies:
// one thread per slot, 12 copies, write addresses IDENTICAL to R17 (bank-verified
// 2.9e5 conflicts) -> kills the per-stage input split8 VALU. MFMA sequence unchanged
// -> bit-identical output.
__global__ __launch_bounds__(256, 2) void conv_mfma_k(
    const short* __restrict__ Ib, const short* __restrict__ Wb,
    const float* __restrict__ bias, float* __restrict__ out) {
  __shared__ short Slds[3 * 264 * 32];   // [plane][r*66+xx][32c] 50,688 B
  __shared__ short Wl[3 * 128 * 32];     // [plane][ko][32c]     24,576 B
  const int tid = threadIdx.x;
  const int wave = tid >> 6, lane = tid & 63;
  const int lm = lane & 15, lg = lane >> 4;
  const int pos0 = blockIdx.x * 128;
  const int ko0  = blockIdx.y * 128;
  const int b    = blockIdx.z;
  const int y0   = pos0 >> 6;            // first of 2 output rows

  f32x4_t acc[2][8];
  #pragma unroll
  for (int f = 0; f < 2; ++f)
    #pragma unroll
    for (int p = 0; p < 8; ++p) acc[f][p] = (f32x4_t){0.f, 0.f, 0.f, 0.f};

  // weight prefetch registers: 2 staging tasks/thread x 3 planes
  short8_t pf[2][3];
#define PREF(TAP, C0S)                                                          \
  { _Pragma("unroll")                                                           \
    for (int t_ = 0; t_ < 2; ++t_) {                                            \
      const int i_ = tid + t_ * 256;                                            \
      const int kol_ = i_ >> 2, part_ = i_ & 3;                                 \
      const size_t g_ = (((size_t)(TAP) * 3) * 512 + ko0 + kol_) * 512 + (C0S) + (part_ << 3); \
      pf[t_][0] = *(const short8_t*)(Wb + g_);                                  \
      pf[t_][1] = *(const short8_t*)(Wb + g_ + 262144);                         \
      pf[t_][2] = *(const short8_t*)(Wb + g_ + 524288);                         \
    } }

  PREF(0, 0)   // prologue: tap 0 of stage 0

  for (int c0 = 0; c0 < 512; c0 += 32) {
    __syncthreads();   // protect previous stage's Slds reads
    // ---- stage input: 264 slots x 3 planes x 4 parts, raw 16B copies ----
    for (int i = tid; i < 264; i += 256) {
      const int r = i / 66, xx = i - r * 66;
      const int gy = y0 + r - 1, gx = xx - 1;
      const bool ok = ((unsigned)gy < 64u) && ((unsigned)gx < 64u);
      const size_t src = ((((size_t)b << 12) + (gy << 6) + gx) << 9) + c0;
      const int sw = (xx >> 1) & 3;
      char* drow = (char*)Slds + (i << 6);
      #pragma unroll
      for (int pl = 0; pl < 3; ++pl) {
        #pragma unroll
        for (int part = 0; part < 4; ++part) {
          short8_t v = {};
          if (ok) v = *(const short8_t*)(Ib + (size_t)pl * IPLANE + src + (part << 3));
          *(short8_t*)(drow + pl * 16896 + ((part ^ sw) << 4)) = v;
        }
      }
    }
    for (int tap = 0; tap < 9; ++tap) {
      __syncthreads();   // protect previous tap's Wl reads (and input writes for tap 0)
      // ---- write prefetched weights to LDS (no global latency between barriers) ----
      #pragma unroll
      for (int t_ = 0; t_ < 2; ++t_) {
        const int i_ = tid + t_ * 256;
        const int kol_ = i_ >> 2, part_ = i_ & 3;
        char* base = (char*)Wl + (kol_ << 6) + ((part_ ^ ((kol_ >> 1) & 3)) << 4);
        *(short8_t*)(base) = pf[t_][0];
        *(short8_t*)(base + 8192) = pf[t_][1];
        *(short8_t*)(base + 16384) = pf[t_][2];
      }
      __syncthreads();
      // ---- prefetch next tap's weights (hidden under this tap's MFMAs) ----
      {
        const int ntap = (tap == 8) ? 0 : tap + 1;
        const int nc0  = (tap == 8) ? ((c0 + 32 < 512) ? c0 + 32 : c0) : c0;
        PREF(ntap, nc0)
      }
      const int dy = tap / 3, dx = tap - dy * 3;
      // ---- A fragments (weights) ----
      short8_t Ah[2], Am[2], Al[2];
      #pragma unroll
      for (int f = 0; f < 2; ++f) {
        int kol = (wave << 5) + (f << 4) + lm;
        char* ab = (char*)Wl + (kol << 6) + ((lg ^ ((kol >> 1) & 3)) << 4);
        Ah[f] = *(short8_t*)ab;
        Am[f] = *(short8_t*)(ab + 8192);
        Al[f] = *(short8_t*)(ab + 16384);
      }
      // ---- B fragments + MFMAs ----
      #pragma unroll
      for (int p = 0; p < 8; ++p) {
        const int yl = p >> 2;
        const int x  = ((p & 3) << 4) + lm;
        const int r  = yl + dy, xx = x + dx;
        char* bb = (char*)Slds + ((r * 66 + xx) << 6) + ((lg ^ ((xx >> 1) & 3)) << 4);
        short8_t Bh = *(short8_t*)bb;
        short8_t Bm = *(short8_t*)(bb + 16896);
        short8_t Bl = *(short8_t*)(bb + 33792);
        #pragma unroll
        for (int f = 0; f < 2; ++f) {
          acc[f][p] = __builtin_amdgcn_mfma_f32_16x16x32_bf16(Ah[f], Bh, acc[f][p], 0, 0, 0);
          acc[f][p] = __builtin_amdgcn_mfma_f32_16x16x32_bf16(Ah[f], Bm, acc[f][p], 0, 0, 0);
          acc[f][p] = __builtin_amdgcn_mfma_f32_16x16x32_bf16(Am[f], Bh, acc[f][p], 0, 0, 0);
          acc[f][p] = __builtin_amdgcn_mfma_f32_16x16x32_bf16(Ah[f], Bl, acc[f][p], 0, 0, 0);
          acc[f][p] = __builtin_amdgcn_mfma_f32_16x16x32_bf16(Al[f], Bh, acc[f][p], 0, 0, 0);
          acc[f][p] = __builtin_amdgcn_mfma_f32_16x16x32_bf16(Am[f], Bm, acc[f][p], 0, 0, 0);
        }
      }
    }
  }
#undef PREF
  // ---- epilogue: bias + relu; C/D: col(pos)=lane&15, row(ko)=(lane>>4)*4+reg ----
  #pragma unroll
  for (int f = 0; f < 2; ++f) {
    const int koB = ko0 + (wave << 5) + (f << 4) + (lg << 2);
    #pragma unroll
    for (int reg = 0; reg < 4; ++reg) {
      const float bv = bias[koB + reg];
      #pragma unroll
      for (int p = 0; p < 8; ++p) {
        const int pos = pos0 + (p << 4) + lm;
        out[(((size_t)b * 512 + koB + reg) << 12) + pos] = fmaxf(acc[f][p][reg] + bv, 0.f);
      }
    }
  }
}

// ---------------- 1x1 heads via MFMA: 54 (pad 64) x 512 x 4096/batch ----------------
__global__ __launch_bounds__(256, 4) void head_mfma_k(
    const float* __restrict__ conv, const float* __restrict__ Wcls,
    const float* __restrict__ bcls, const float* __restrict__ Wbbox,
    const float* __restrict__ bbbox, float* __restrict__ head) {
  __shared__ short Bl[3 * 64 * 32];    // [plane][pos][32c] 12,288 B
  __shared__ short Al[3 * 64 * 32];    // [plane][ko][32c]  12,288 B
  const int tid = threadIdx.x;
  const int wave = tid >> 6, lane = tid & 63;
  const int lm = lane & 15, lg = lane >> 4;
  const int pos0 = blockIdx.x * 64;
  const int b    = blockIdx.y;

  f32x4_t acc[4];
  #pragma unroll
  for (int f = 0; f < 4; ++f) acc[f] = (f32x4_t){0.f, 0.f, 0.f, 0.f};

  const float* cb = conv + ((size_t)b * 512 << 12);

  for (int c0 = 0; c0 < 512; c0 += 32) {
    __syncthreads();
    {
      const int pos_l = tid & 63, ch = tid >> 6;
      float v[8];
      #pragma unroll
      for (int j = 0; j < 8; ++j)
        v[j] = cb[((size_t)(c0 + ch * 8 + j) << 12) + pos0 + pos_l];
      short8_t h, m, l;
      split8(make_float4(v[0], v[1], v[2], v[3]), make_float4(v[4], v[5], v[6], v[7]), h, m, l);
      char* base = (char*)Bl + (pos_l << 6) + ((ch ^ ((pos_l >> 1) & 3)) << 4);
      *(short8_t*)(base) = h;
      *(short8_t*)(base + 4096) = m;
      *(short8_t*)(base + 8192) = l;
    }
    {
      const int ko = tid >> 2, part = tid & 3;
      float4 wa = {}, wb = {};
      if (ko < 54) {
        const float* src = (ko < 18) ? (Wcls + (size_t)ko * 512) : (Wbbox + (size_t)(ko - 18) * 512);
        wa = *(const float4*)(src + c0 + part * 8);
        wb = *(const float4*)(src + c0 + part * 8 + 4);
      }
      short8_t h, m, l;
      split8(wa, wb, h, m, l);
      char* base = (char*)Al + (ko << 6) + ((part ^ ((ko >> 1) & 3)) << 4);
      *(short8_t*)(base) = h;
      *(short8_t*)(base + 4096) = m;
      *(short8_t*)(base + 8192) = l;
    }
    __syncthreads();
    short8_t Bh, Bm, Bv;
    {
      const int pos_l = (wave << 4) + lm;
      char* bb = (char*)Bl + (pos_l << 6) + ((lg ^ ((pos_l >> 1) & 3)) << 4);
      Bh = *(short8_t*)bb;
      Bm = *(short8_t*)(bb + 4096);
      Bv = *(short8_t*)(bb + 8192);
    }
    #pragma unroll
    for (int f = 0; f < 4; ++f) {
      const int kol = (f << 4) + lm;
      char* ab = (char*)Al + (kol << 6) + ((lg ^ ((kol >> 1) & 3)) << 4);
      short8_t Ah = *(short8_t*)ab;
      short8_t Am = *(short8_t*)(ab + 4096);
      short8_t Av = *(short8_t*)(ab + 8192);
      acc[f] = __builtin_amdgcn_mfma_f32_16x16x32_bf16(Ah, Bh, acc[f], 0, 0, 0);
      acc[f] = __builtin_amdgcn_mfma_f32_16x16x32_bf16(Ah, Bm, acc[f], 0, 0, 0);
      acc[f] = __builtin_amdgcn_mfma_f32_16x16x32_bf16(Am, Bh, acc[f], 0, 0, 0);
      acc[f] = __builtin_amdgcn_mfma_f32_16x16x32_bf16(Ah, Bv, acc[f], 0, 0, 0);
      acc[f] = __builtin_amdgcn_mfma_f32_16x16x32_bf16(Av, Bh, acc[f], 0, 0, 0);
      acc[f] = __builtin_amdgcn_mfma_f32_16x16x32_bf16(Am, Bm, acc[f], 0, 0, 0);
    }
  }
  #pragma unroll
  for (int f = 0; f < 4; ++f) {
    #pragma unroll
    for (int reg = 0; reg < 4; ++reg) {
      const int ko = (f << 4) + (lg << 2) + reg;
      if (ko < 54) {
        const float bv = (ko < 18) ? bcls[ko] : bbbox[ko - 18];
        const int pos = pos0 + (wave << 4) + lm;
        head[(((size_t)b * 54 + ko) << 12) + pos] = acc[f][reg] + bv;
      }
    }
  }
}

// ---------------- score + box decode + clip + LDS histogram (pos-major) ----------------
__global__ __launch_bounds__(256) void decode_k(
    const float* __restrict__ head, const float* __restrict__ im_info,
    float* __restrict__ boxes, unsigned* __restrict__ skeys, unsigned* __restrict__ hist) {
  __shared__ unsigned hl[4096];
  const int tid = threadIdx.x;
  #pragma unroll
  for (int i = 0; i < 16; ++i) hl[tid + i * 256] = 0u;
  __syncthreads();
  const int p = blockIdx.x * 256 + tid;
  const int b = p >> 12; const int pos = p & 4095;
  const int x = pos & 63; const int y = pos >> 6;
  const float* hb = head + ((size_t)b * 54 << 12);
  const float imh = im_info[b * 3 + 0], imw = im_info[b * 3 + 1];
  float s[18];
  #pragma unroll
  for (int o = 0; o < 18; ++o) s[o] = hb[(o << 12) + pos];
  float d[36];
  #pragma unroll
  for (int o = 0; o < 36; ++o) d[o] = hb[((18 + o) << 12) + pos];
  const float sx = x * 16.f, sy = y * 16.f;
  #pragma unroll
  for (int a = 0; a < 9; ++a) {
    const float s0 = s[a], s1 = s[9 + a];
    const float m = fmaxf(s0, s1);
    const float e0 = expf(s0 - m), e1 = expf(s1 - m);
    const float score = e1 / (e0 + e1);
    const float d0 = d[a * 4 + 0], d1 = d[a * 4 + 1];
    const float d2 = d[a * 4 + 2], d3 = d[a * 4 + 3];
    const float ax1 = A9c[a][0] + sx, ay1 = A9c[a][1] + sy;
    const float ax2 = A9c[a][2] + sx, ay2 = A9c[a][3] + sy;
    const float aw = ax2 - ax1 + 1.f, ah = ay2 - ay1 + 1.f;
    const float acx = ax1 + 0.5f * aw, acy = ay1 + 0.5f * ah;
    const float pcx = d0 * aw + acx, pcy = d1 * ah + acy;
    const float pw = expf(d2) * aw, ph = expf(d3) * ah;
    const float x1 = fminf(fmaxf(pcx - 0.5f * pw, 0.f), imw - 1.f);
    const float y1 = fminf(fmaxf(pcy - 0.5f * ph, 0.f), imh - 1.f);
    const float x2 = fminf(fmaxf(pcx + 0.5f * pw, 0.f), imw - 1.f);
    const float y2 = fminf(fmaxf(pcy + 0.5f * ph, 0.f), imh - 1.f);
    const int n = pos * 9 + a;
    *(float4*)&boxes[((size_t)b * NANCH + n) * 4] = make_float4(x1, y1, x2, y2);
    const unsigned key = __float_as_uint(score);
    skeys[(size_t)b * NANCH + n] = key;
    atomicAdd(&hl[key >> 20], 1u);
  }
  __syncthreads();
  #pragma unroll
  for (int i = 0; i < 16; ++i) {
    unsigned c = hl[tid + i * 256];
    if (c) atomicAdd(&hist[b * 4096 + tid + i * 256], c);
  }
}

// ---------------- fused threshold select + compact (one block per batch, 512 thr) ------
__global__ __launch_bounds__(512) void select_k(
    const unsigned* __restrict__ skeys, const unsigned* __restrict__ hist,
    unsigned* __restrict__ misc, unsigned* __restrict__ ckey,
    unsigned* __restrict__ cidx) {
  const int b = blockIdx.x;
  const int tid = threadIdx.x;
  __shared__ unsigned csum[256];
  __shared__ unsigned hl2[256];
  __shared__ unsigned s_t1, s_cumAbove, s_T2, s_cnt;
  const unsigned* h = hist + b * 4096;
  if (tid < 256) {
    unsigned s = 0;
    #pragma unroll
    for (int i = 0; i < 16; ++i) s += h[tid * 16 + i];
    csum[tid] = s;
    hl2[tid] = 0u;
  }
  __syncthreads();
  if (tid == 0) {
    unsigned cum = 0; int chunk = 0;
    for (int c = 255; c >= 0; --c) {
      if (cum + csum[c] >= (unsigned)PRE_TOPN) { chunk = c; break; }
      cum += csum[c];
    }
    unsigned t1 = chunk * 16, cumAbove = cum;
    for (int i = 15; i >= 0; --i) {
      unsigned cnt = h[chunk * 16 + i];
      if (cum + cnt >= (unsigned)PRE_TOPN) { t1 = chunk * 16 + i; cumAbove = cum; break; }
      cum += cnt;
    }
    s_t1 = t1; s_cumAbove = cumAbove; s_cnt = 0u;
  }
  __syncthreads();
  const unsigned t1 = s_t1;
  const unsigned* sk = skeys + (size_t)b * NANCH;
  for (int t = tid; t < NANCH; t += 512) {
    unsigned key = sk[t];
    if ((key >> 20) == t1) atomicAdd(&hl2[(key >> 12) & 255u], 1u);
  }
  __syncthreads();
  if (tid == 0) {
    unsigned cum = s_cumAbove;
    unsigned T2 = t1 << 20;
    for (int ss = 255; ss >= 0; --ss) {
      unsigned c = hl2[ss];
      if (cum + c >= (unsigned)PRE_TOPN) { T2 = (t1 << 20) | ((unsigned)ss << 12); break; }
      cum += c;
    }
    s_T2 = T2;
  }
  __syncthreads();
  const unsigned T2 = s_T2;
  const int lane = tid & 63;
  for (int t = tid; t < NANCH; t += 512) {
    unsigned key = sk[t];
    bool pred = key >= T2;
    unsigned long long mb = __ballot(pred);
    unsigned base = 0;
    if (lane == 0) base = atomicAdd(&s_cnt, (unsigned)__popcll(mb));
    base = (unsigned)__shfl((int)base, 0, 64);
    if (pred) {
      unsigned pp = base + (unsigned)__popcll(mb & ((1ull << lane) - 1ull));
      if (pp < (unsigned)CAND_CAP) {
        ckey[(size_t)b * CAND_CAP + pp] = key;
        cidx[(size_t)b * CAND_CAP + pp] = (unsigned)t;
      }
    }
  }
  __syncthreads();
  if (tid == 0) misc[12 + b] = s_cnt;
}

// ---------------- exact rank sort of candidates (desc score, asc index) ----------------
__global__ __launch_bounds__(256) void rank_scatter_k(
    const unsigned* __restrict__ ckey, const unsigned* __restrict__ cidx,
    const unsigned* __restrict__ misc, const float* __restrict__ boxes,
    float* __restrict__ sbox) {
  const int b = blockIdx.y;
  const int K = min((int)misc[12 + b], CAND_CAP);
  if (blockIdx.x * 256 >= (unsigned)K) return;   // inactive block: nothing to write
  const int i = blockIdx.x * 256 + threadIdx.x;
  unsigned mykey = 0, myidx = 0;
  const bool active = i < K;
  if (active) {
    mykey = ckey[(size_t)b * CAND_CAP + i];
    myidx = cidx[(size_t)b * CAND_CAP + i];
  }
  int rank = 0;
  __shared__ unsigned skey[1024];
  __shared__ unsigned sidx[1024];
  for (int c0 = 0; c0 < K; c0 += 1024) {
    int n = min(1024, K - c0);
    __syncthreads();
    for (int e = threadIdx.x; e < n; e += 256) {
      skey[e] = ckey[(size_t)b * CAND_CAP + c0 + e];
      sidx[e] = cidx[(size_t)b * CAND_CAP + c0 + e];
    }
    __syncthreads();
    if (active) {
      for (int j = 0; j < n; ++j) {
        unsigned kj = skey[j];
        rank += (kj > mykey) || (kj == mykey && sidx[j] < myidx);
      }
    }
  }
  if (active && rank < PRE_TOPN) {
    float4 bx = *(const float4*)&boxes[((size_t)b * NANCH + myidx) * 4];
    *(float4*)&sbox[((size_t)b * PRE_TOPN + rank) * 4] = bx;
  }
}

// ---------------- fused greedy NMS: tile-sequential, no bit-matrix ----------------
__global__ __launch_bounds__(256) void nms_fused_k(const float* __restrict__ sbox,
                                                   float* __restrict__ out) {
  __shared__ float4 tb[64];                 // current tile's boxes
  __shared__ float4 pk[POST_TOPN];          // picked boxes
  __shared__ unsigned long long supw[4];    // per-wave suppression ballots
  __shared__ int s_np;
  const int b = blockIdx.x;
  const int tid = threadIdx.x;
  const int wv = tid >> 6, lane = tid & 63;
  const float* S = sbox + (size_t)b * PRE_TOPN * 4;
  float* O = out + (size_t)b * POST_TOPN * 5;
  if (tid == 0) s_np = 0;
  int np = 0;

  for (int t = 0; t < (PRE_TOPN + 63) / 64; ++t) {
    __syncthreads();                        // prev phase-2 done (pk, s_np final)
    np = s_np;
    if (np >= POST_TOPN) break;
    const int nt = min(64, PRE_TOPN - t * 64);
    if (tid < 64 && tid < nt) tb[tid] = *(const float4*)&S[(size_t)(t * 64 + tid) * 4];
    __syncthreads();                        // tb staged
    // ---- phase 1: suppression of tile boxes by existing picks ----
    const float4 q = tb[lane < nt ? lane : 0];
    const float qarea = (q.z - q.x + 1.f) * (q.w - q.y + 1.f);
    bool sup = false;
    for (int p = wv; p < np; p += 4) {
      const float4 pb = pk[p];
      const float pa = (pb.z - pb.x + 1.f) * (pb.w - pb.y + 1.f);
      const float xx1 = fmaxf(pb.x, q.x), yy1 = fmaxf(pb.y, q.y);
      const float xx2 = fminf(pb.z, q.z), yy2 = fminf(pb.w, q.w);
      const float inter = fmaxf(xx2 - xx1 + 1.f, 0.f) * fmaxf(yy2 - yy1 + 1.f, 0.f);
      const float iou = inter / (pa + qarea - inter);
      sup = sup || (iou > 0.7f);
    }
    unsigned long long bal = __ballot(sup);
    if (lane == 0) supw[wv] = bal;
    __syncthreads();
    // ---- phase 2: wave 0 resolves intra-tile picks serially ----
    if (wv == 0) {
      const unsigned long long validm = (nt == 64) ? ~0ull : ((1ull << nt) - 1ull);
      unsigned long long remaining = validm & ~(supw[0] | supw[1] | supw[2] | supw[3]);
      while (remaining && np < POST_TOPN) {
        const int jj = __ffsll((long long)remaining) - 1;
        const float4 pb = tb[jj];
        if (lane == 0) {
          pk[np] = pb;
          O[np * 5 + 0] = (float)b;
          O[np * 5 + 1] = pb.x; O[np * 5 + 2] = pb.y;
          O[np * 5 + 3] = pb.z; O[np * 5 + 4] = pb.w;
        }
        const float pa = (pb.z - pb.x + 1.f) * (pb.w - pb.y + 1.f);
        const float xx1 = fmaxf(pb.x, q.x), yy1 = fmaxf(pb.y, q.y);
        const float xx2 = fminf(pb.z, q.z), yy2 = fminf(pb.w, q.w);
        const float inter = fmaxf(xx2 - xx1 + 1.f, 0.f) * fmaxf(yy2 - yy1 + 1.f, 0.f);
        const float iou = inter / (pa + qarea - inter);
        remaining &= ~__ballot(iou > 0.7f);   // self IoU = 1 clears bit jj
        ++np;
      }
      if (lane == 0) s_np = np;
    }
  }
  __syncthreads();
  np = s_np;
  for (int e = tid; e < (POST_TOPN - np) * 5; e += 256) {
    int r = np + e / 5; int c = e - (e / 5) * 5;
    O[r * 5 + c] = (c == 0) ? (float)b : 0.f;
  }
}

// ---------------- launch ----------------
extern "C" void kernel_launch(void* const* d_in, const int* in_sizes, int n_in,
                              void* d_out, int out_size, void* d_ws, size_t ws_size,
                              hipStream_t stream) {
  const float* base_feat = (const float*)d_in[0];
  const float* im_info   = (const float*)d_in[1];
  const float* W_conv    = (const float*)d_in[4];
  const float* b_conv    = (const float*)d_in[5];
  const float* W_cls     = (const float*)d_in[6];
  const float* b_cls     = (const float*)d_in[7];
  const float* W_bbox    = (const float*)d_in[8];
  const float* b_bbox    = (const float*)d_in[9];
  float* out = (float*)d_out;
  char* ws = (char*)d_ws;

  short*    Wb    = (short*)(ws + OFF_WB);
  short*    Ib    = (short*)(ws + OFF_IB);
  float*    conv  = (float*)(ws + OFF_CONV);
  float*    head  = (float*)(ws + OFF_HEAD);   // overlays Wb (dead after conv)
  unsigned* skeys = (unsigned*)(ws + OFF_SKEY);
  float*    boxes = (float*)(ws + OFF_BOX);
  unsigned* hist  = (unsigned*)(ws + OFF_HIST);
  unsigned* misc  = (unsigned*)(ws + OFF_MISC);
  unsigned* ckey  = (unsigned*)(ws + OFF_CKEY);
  unsigned* cidx  = (unsigned*)(ws + OFF_CIDX);
  float*    sbox  = (float*)(ws + OFF_SBOX);

  hipMemsetAsync(ws + OFF_HIST, 0, 65536 + 256, stream);

  wsplit_k<<<9216, 256, 0, stream>>>(W_conv, Wb);
  cvt_split_k<<<dim3(64, 8, 4), 256, 0, stream>>>(base_feat, Ib);
  conv_mfma_k<<<dim3(32, 4, 4), 256, 0, stream>>>(Ib, Wb, b_conv, conv);
  head_mfma_k<<<dim3(64, 4), 256, 0, stream>>>(conv, W_cls, b_cls, W_bbox, b_bbox, head);
  decode_k<<<64, 256, 0, stream>>>(head, im_info, boxes, skeys, hist);
  select_k<<<4, 512, 0, stream>>>(skeys, hist, misc, ckey, cidx);
  rank_scatter_k<<<dim3(CAND_CAP / 256, 4), 256, 0, stream>>>(ckey, cidx, misc, boxes, sbox);
  nms_fused_k<<<4, 256, 0, stream>>>(sbox, out);
}

// Round 19
// 730.107 us; speedup vs baseline: 1.0149x; 1.0149x over previous
//
#include <hip/hip_runtime.h>
#include <math.h>

// ---------------- problem constants ----------------
constexpr int NB = 4;            // batch
constexpr int NC = 512;          // channels
constexpr int NH = 64, NW = 64;  // spatial
constexpr int NPOS = NH * NW;        // 4096
constexpr int NANCH = NPOS * 9;      // 36864 anchors/batch
constexpr int PRE_TOPN = 6000;
constexpr int POST_TOPN = 300;
constexpr int CAND_CAP = 40960;

typedef short short8_t __attribute__((ext_vector_type(8)));
typedef float f32x4_t __attribute__((ext_vector_type(4)));

// anchors for base_size=16, ratios {0.5,1,2}, scales {8,16,32} (verified vs numpy)
__device__ __constant__ float A9c[9][4] = {
  {-84.f,-40.f,99.f,55.f},   {-176.f,-88.f,191.f,103.f}, {-360.f,-184.f,375.f,199.f},
  {-56.f,-56.f,71.f,71.f},   {-120.f,-120.f,135.f,135.f},{-248.f,-248.f,263.f,263.f},
  {-36.f,-80.f,51.f,95.f},   {-80.f,-168.f,95.f,183.f},  {-168.f,-344.f,183.f,359.f}};

// ---------------- ws layout (bytes) ----------------
constexpr size_t OFF_WB   = 0;          // 9*3*512*512*2 = 14,155,776 (bf16 W planes; dead after conv)
constexpr size_t OFF_IT   = 14155776;   // 4*4096*512*4  = 33,554,432 (fp32 input [b][pos][c]; dead after conv)
constexpr size_t OFF_CONV = 47710208;   // 4*512*4096*4  = 33,554,432
constexpr size_t OFF_HIST = 81264640;   // 65,536
constexpr size_t OFF_MISC = 81330176;   // 256
// overlays (written only after their host region is dead):
constexpr size_t OFF_HEAD = 0;          // 3,538,944 (inside WB, after conv)
constexpr size_t OFF_SKEY = 3538944;    // 589,824
constexpr size_t OFF_BOX  = 4128768;    // 2,359,296
constexpr size_t OFF_CKEY = 6488064;    // 655,360
constexpr size_t OFF_CIDX = 7143424;    // 655,360
constexpr size_t OFF_SBOX = 7798784;    // 384,000 -> end 8,182,784 < 14,155,776 OK
// total ws = 81,330,432 bytes

// ---------------- bf16 helpers (RNE) ----------------
__device__ inline unsigned short f2bf(float f) {
  unsigned u = __float_as_uint(f);
  unsigned r = u + 0x7fffu + ((u >> 16) & 1u);
  return (unsigned short)(r >> 16);
}
__device__ inline float bf2f(unsigned short h) { return __uint_as_float(((unsigned)h) << 16); }

// split 8 floats into hi/mid/lo bf16 (24 mantissa bits total)
__device__ inline void split8(const float4 A, const float4 B, short8_t& h, short8_t& m, short8_t& l) {
#define SPL(J, X) { unsigned short hh = f2bf(X); float fh = bf2f(hh); \
                    unsigned short mm = f2bf((X) - fh); float fm = bf2f(mm); \
                    unsigned short ll = f2bf((X) - fh - fm); \
                    h[J] = (short)hh; m[J] = (short)mm; l[J] = (short)ll; }
  SPL(0, A.x) SPL(1, A.y) SPL(2, A.z) SPL(3, A.w)
  SPL(4, B.x) SPL(5, B.y) SPL(6, B.z) SPL(7, B.w)
#undef SPL
}

// ---------------- merged prep: weight pre-split + input transpose (one launch) --------
// blocks [0, 9216): W[ko][c][tap] fp32 -> Wb[tap][plane][ko][c] bf16 (same f2bf chain)
// blocks [9216, 11264): input [b][c][pos] -> It [b][pos][c] fp32 (64x64 LDS tile)
__global__ __launch_bounds__(256) void prep_k(const float* __restrict__ Wc,
                                              short* __restrict__ Wb,
                                              const float* __restrict__ in,
                                              float* __restrict__ It) {
  __shared__ float T[64][65];
  const int tid = threadIdx.x;
  if (blockIdx.x < 9216) {
    const int i = blockIdx.x * 256 + tid;
    const int tap = i >> 18;
    const int ko = (i >> 9) & 511, c = i & 511;
    const float w = Wc[(size_t)ko * 4608 + c * 9 + tap];
    const unsigned short h = f2bf(w);
    const float fh = bf2f(h);
    const unsigned short m = f2bf(w - fh);
    const float fm = bf2f(m);
    const unsigned short l = f2bf(w - fh - fm);
    const size_t base = ((size_t)tap * 3 * 512 + ko) * 512 + c;
    Wb[base] = (short)h;
    Wb[base + 512 * 512] = (short)m;
    Wb[base + 2 * 512 * 512] = (short)l;
  } else {
    const int id = blockIdx.x - 9216;          // 2048 blocks: x=pos0(64), y=c0(8), z=b(4)
    const int pos0 = (id & 63) * 64;
    const int c0 = ((id >> 6) & 7) * 64;
    const int b = id >> 9;
    for (int i = tid; i < 4096; i += 256) {
      int cc = i >> 6, pp = i & 63;
      T[cc][pp] = in[(((size_t)b * 512 + c0 + cc) << 12) + pos0 + pp];
    }
    __syncthreads();
    for (int i = tid; i < 4096; i += 256) {
      int pp = i >> 6, cc = i & 63;
      It[((((size_t)b << 12) + pos0 + pp) << 9) + c0 + cc] = T[cc][pp];
    }
  }
}

// ---------------- conv3x3 + bias + relu via MFMA (bf16x3, T14 weight prefetch) --------
// EXACT R17 kernel (best measured config: 733.6 us total). Input staged from fp32 It
// with in-kernel split8; weights prefetched from pre-split Wb planes.
__global__ __launch_bounds__(256, 2) void conv_mfma_k(
    const float* __restrict__ It, const short* __restrict__ Wb,
    const float* __restrict__ bias, float* __restrict__ out) {
  __shared__ short Slds[3 * 264 * 32];   // [plane][r*66+xx][32c] 50,688 B
  __shared__ short Wl[3 * 128 * 32];     // [plane][ko][32c]     24,576 B
  const int tid = threadIdx.x;
  const int wave = tid >> 6, lane = tid & 63;
  const int lm = lane & 15, lg = lane >> 4;
  const int pos0 = blockIdx.x * 128;
  const int ko0  = blockIdx.y * 128;
  const int b    = blockIdx.z;
  const int y0   = pos0 >> 6;            // first of 2 output rows

  f32x4_t acc[2][8];
  #pragma unroll
  for (int f = 0; f < 2; ++f)
    #pragma unroll
    for (int p = 0; p < 8; ++p) acc[f][p] = (f32x4_t){0.f, 0.f, 0.f, 0.f};

  // weight prefetch registers: 2 staging tasks/thread x 3 planes
  short8_t pf[2][3];
#define PREF(TAP, C0S)                                                          \
  { _Pragma("unroll")                                                           \
    for (int t_ = 0; t_ < 2; ++t_) {                                            \
      const int i_ = tid + t_ * 256;                                            \
      const int kol_ = i_ >> 2, part_ = i_ & 3;                                 \
      const size_t g_ = (((size_t)(TAP) * 3) * 512 + ko0 + kol_) * 512 + (C0S) + (part_ << 3); \
      pf[t_][0] = *(const short8_t*)(Wb + g_);                                  \
      pf[t_][1] = *(const short8_t*)(Wb + g_ + 262144);                         \
      pf[t_][2] = *(const short8_t*)(Wb + g_ + 524288);                         \
    } }

  PREF(0, 0)   // prologue: tap 0 of stage 0

  for (int c0 = 0; c0 < 512; c0 += 32) {
    __syncthreads();   // protect previous stage's Slds reads
    // ---- stage input: 264 slots (4 rows x 66 xx) x 32 c, fp32 -> 3 bf16 planes ----
    for (int i = tid; i < 264; i += 256) {
      int r = i / 66, xx = i - r * 66;
      int gy = y0 + r - 1, gx = xx - 1;
      bool ok = ((unsigned)gy < 64u) && ((unsigned)gx < 64u);
      float4 f0 = {}, f1 = {}, f2 = {}, f3 = {}, f4 = {}, f5 = {}, f6 = {}, f7 = {};
      if (ok) {
        const float4* gp = (const float4*)(It + ((((size_t)b << 12) + (gy << 6) + gx) << 9) + c0);
        f0 = gp[0]; f1 = gp[1]; f2 = gp[2]; f3 = gp[3];
        f4 = gp[4]; f5 = gp[5]; f6 = gp[6]; f7 = gp[7];
      }
      const int sw = (xx >> 1) & 3;
      char* drow = (char*)Slds + (i << 6);
      short8_t h, m, l;
      split8(f0, f1, h, m, l);
      *(short8_t*)(drow + ((0 ^ sw) << 4)) = h;
      *(short8_t*)(drow + 16896 + ((0 ^ sw) << 4)) = m;
      *(short8_t*)(drow + 33792 + ((0 ^ sw) << 4)) = l;
      split8(f2, f3, h, m, l);
      *(short8_t*)(drow + ((1 ^ sw) << 4)) = h;
      *(short8_t*)(drow + 16896 + ((1 ^ sw) << 4)) = m;
      *(short8_t*)(drow + 33792 + ((1 ^ sw) << 4)) = l;
      split8(f4, f5, h, m, l);
      *(short8_t*)(drow + ((2 ^ sw) << 4)) = h;
      *(short8_t*)(drow + 16896 + ((2 ^ sw) << 4)) = m;
      *(short8_t*)(drow + 33792 + ((2 ^ sw) << 4)) = l;
      split8(f6, f7, h, m, l);
      *(short8_t*)(drow + ((3 ^ sw) << 4)) = h;
      *(short8_t*)(drow + 16896 + ((3 ^ sw) << 4)) = m;
      *(short8_t*)(drow + 33792 + ((3 ^ sw) << 4)) = l;
    }
    for (int tap = 0; tap < 9; ++tap) {
      __syncthreads();   // protect previous tap's Wl reads (and input writes for tap 0)
      // ---- write prefetched weights to LDS (no global latency between barriers) ----
      #pragma unroll
      for (int t_ = 0; t_ < 2; ++t_) {
        const int i_ = tid + t_ * 256;
        const int kol_ = i_ >> 2, part_ = i_ & 3;
        char* base = (char*)Wl + (kol_ << 6) + ((part_ ^ ((kol_ >> 1) & 3)) << 4);
        *(short8_t*)(base) = pf[t_][0];
        *(short8_t*)(base + 8192) = pf[t_][1];
        *(short8_t*)(base + 16384) = pf[t_][2];
      }
      __syncthreads();
      // ---- prefetch next tap's weights (hidden under this tap's MFMAs) ----
      {
        const int ntap = (tap == 8) ? 0 : tap + 1;
        const int nc0  = (tap == 8) ? ((c0 + 32 < 512) ? c0 + 32 : c0) : c0;
        PREF(ntap, nc0)
      }
      const int dy = tap / 3, dx = tap - dy * 3;
      // ---- A fragments (weights) ----
      short8_t Ah[2], Am[2], Al[2];
      #pragma unroll
      for (int f = 0; f < 2; ++f) {
        int kol = (wave << 5) + (f << 4) + lm;
        char* ab = (char*)Wl + (kol << 6) + ((lg ^ ((kol >> 1) & 3)) << 4);
        Ah[f] = *(short8_t*)ab;
        Am[f] = *(short8_t*)(ab + 8192);
        Al[f] = *(short8_t*)(ab + 16384);
      }
      // ---- B fragments + MFMAs ----
      #pragma unroll
      for (int p = 0; p < 8; ++p) {
        const int yl = p >> 2;
        const int x  = ((p & 3) << 4) + lm;
        const int r  = yl + dy, xx = x + dx;
        char* bb = (char*)Slds + ((r * 66 + xx) << 6) + ((lg ^ ((xx >> 1) & 3)) << 4);
        short8_t Bh = *(short8_t*)bb;
        short8_t Bm = *(short8_t*)(bb + 16896);
        short8_t Bl = *(short8_t*)(bb + 33792);
        #pragma unroll
        for (int f = 0; f < 2; ++f) {
          acc[f][p] = __builtin_amdgcn_mfma_f32_16x16x32_bf16(Ah[f], Bh, acc[f][p], 0, 0, 0);
          acc[f][p] = __builtin_amdgcn_mfma_f32_16x16x32_bf16(Ah[f], Bm, acc[f][p], 0, 0, 0);
          acc[f][p] = __builtin_amdgcn_mfma_f32_16x16x32_bf16(Am[f], Bh, acc[f][p], 0, 0, 0);
          acc[f][p] = __builtin_amdgcn_mfma_f32_16x16x32_bf16(Ah[f], Bl, acc[f][p], 0, 0, 0);
          acc[f][p] = __builtin_amdgcn_mfma_f32_16x16x32_bf16(Al[f], Bh, acc[f][p], 0, 0, 0);
          acc[f][p] = __builtin_amdgcn_mfma_f32_16x16x32_bf16(Am[f], Bm, acc[f][p], 0, 0, 0);
        }
      }
    }
  }
#undef PREF
  // ---- epilogue: bias + relu; C/D: col(pos)=lane&15, row(ko)=(lane>>4)*4+reg ----
  #pragma unroll
  for (int f = 0; f < 2; ++f) {
    const int koB = ko0 + (wave << 5) + (f << 4) + (lg << 2);
    #pragma unroll
    for (int reg = 0; reg < 4; ++reg) {
      const float bv = bias[koB + reg];
      #pragma unroll
      for (int p = 0; p < 8; ++p) {
        const int pos = pos0 + (p << 4) + lm;
        out[(((size_t)b * 512 + koB + reg) << 12) + pos] = fmaxf(acc[f][p][reg] + bv, 0.f);
      }
    }
  }
}

// ---------------- 1x1 heads via MFMA: 54 (pad 64) x 512 x 4096/batch ----------------
__global__ __launch_bounds__(256, 4) void head_mfma_k(
    const float* __restrict__ conv, const float* __restrict__ Wcls,
    const float* __restrict__ bcls, const float* __restrict__ Wbbox,
    const float* __restrict__ bbbox, float* __restrict__ head) {
  __shared__ short Bl[3 * 64 * 32];    // [plane][pos][32c] 12,288 B
  __shared__ short Al[3 * 64 * 32];    // [plane][ko][32c]  12,288 B
  const int tid = threadIdx.x;
  const int wave = tid >> 6, lane = tid & 63;
  const int lm = lane & 15, lg = lane >> 4;
  const int pos0 = blockIdx.x * 64;
  const int b    = blockIdx.y;

  f32x4_t acc[4];
  #pragma unroll
  for (int f = 0; f < 4; ++f) acc[f] = (f32x4_t){0.f, 0.f, 0.f, 0.f};

  const float* cb = conv + ((size_t)b * 512 << 12);

  for (int c0 = 0; c0 < 512; c0 += 32) {
    __syncthreads();
    {
      const int pos_l = tid & 63, ch = tid >> 6;
      float v[8];
      #pragma unroll
      for (int j = 0; j < 8; ++j)
        v[j] = cb[((size_t)(c0 + ch * 8 + j) << 12) + pos0 + pos_l];
      short8_t h, m, l;
      split8(make_float4(v[0], v[1], v[2], v[3]), make_float4(v[4], v[5], v[6], v[7]), h, m, l);
      char* base = (char*)Bl + (pos_l << 6) + ((ch ^ ((pos_l >> 1) & 3)) << 4);
      *(short8_t*)(base) = h;
      *(short8_t*)(base + 4096) = m;
      *(short8_t*)(base + 8192) = l;
    }
    {
      const int ko = tid >> 2, part = tid & 3;
      float4 wa = {}, wb = {};
      if (ko < 54) {
        const float* src = (ko < 18) ? (Wcls + (size_t)ko * 512) : (Wbbox + (size_t)(ko - 18) * 512);
        wa = *(const float4*)(src + c0 + part * 8);
        wb = *(const float4*)(src + c0 + part * 8 + 4);
      }
      short8_t h, m, l;
      split8(wa, wb, h, m, l);
      char* base = (char*)Al + (ko << 6) + ((part ^ ((ko >> 1) & 3)) << 4);
      *(short8_t*)(base) = h;
      *(short8_t*)(base + 4096) = m;
      *(short8_t*)(base + 8192) = l;
    }
    __syncthreads();
    short8_t Bh, Bm, Bv;
    {
      const int pos_l = (wave << 4) + lm;
      char* bb = (char*)Bl + (pos_l << 6) + ((lg ^ ((pos_l >> 1) & 3)) << 4);
      Bh = *(short8_t*)bb;
      Bm = *(short8_t*)(bb + 4096);
      Bv = *(short8_t*)(bb + 8192);
    }
    #pragma unroll
    for (int f = 0; f < 4; ++f) {
      const int kol = (f << 4) + lm;
      char* ab = (char*)Al + (kol << 6) + ((lg ^ ((kol >> 1) & 3)) << 4);
      short8_t Ah = *(short8_t*)ab;
      short8_t Am = *(short8_t*)(ab + 4096);
      short8_t Av = *(short8_t*)(ab + 8192);
      acc[f] = __builtin_amdgcn_mfma_f32_16x16x32_bf16(Ah, Bh, acc[f], 0, 0, 0);
      acc[f] = __builtin_amdgcn_mfma_f32_16x16x32_bf16(Ah, Bm, acc[f], 0, 0, 0);
      acc[f] = __builtin_amdgcn_mfma_f32_16x16x32_bf16(Am, Bh, acc[f], 0, 0, 0);
      acc[f] = __builtin_amdgcn_mfma_f32_16x16x32_bf16(Ah, Bv, acc[f], 0, 0, 0);
      acc[f] = __builtin_amdgcn_mfma_f32_16x16x32_bf16(Av, Bh, acc[f], 0, 0, 0);
      acc[f] = __builtin_amdgcn_mfma_f32_16x16x32_bf16(Am, Bm, acc[f], 0, 0, 0);
    }
  }
  #pragma unroll
  for (int f = 0; f < 4; ++f) {
    #pragma unroll
    for (int reg = 0; reg < 4; ++reg) {
      const int ko = (f << 4) + (lg << 2) + reg;
      if (ko < 54) {
        const float bv = (ko < 18) ? bcls[ko] : bbbox[ko - 18];
        const int pos = pos0 + (wave << 4) + lm;
        head[(((size_t)b * 54 + ko) << 12) + pos] = acc[f][reg] + bv;
      }
    }
  }
}

// ---------------- score + box decode + clip + LDS histogram (pos-major) ----------------
__global__ __launch_bounds__(256) void decode_k(
    const float* __restrict__ head, const float* __restrict__ im_info,
    float* __restrict__ boxes, unsigned* __restrict__ skeys, unsigned* __restrict__ hist) {
  __shared__ unsigned hl[4096];
  const int tid = threadIdx.x;
  #pragma unroll
  for (int i = 0; i < 16; ++i) hl[tid + i * 256] = 0u;
  __syncthreads();
  const int p = blockIdx.x * 256 + tid;
  const int b = p >> 12; const int pos = p & 4095;
  const int x = pos & 63; const int y = pos >> 6;
  const float* hb = head + ((size_t)b * 54 << 12);
  const float imh = im_info[b * 3 + 0], imw = im_info[b * 3 + 1];
  float s[18];
  #pragma unroll
  for (int o = 0; o < 18; ++o) s[o] = hb[(o << 12) + pos];
  float d[36];
  #pragma unroll
  for (int o = 0; o < 36; ++o) d[o] = hb[((18 + o) << 12) + pos];
  const float sx = x * 16.f, sy = y * 16.f;
  #pragma unroll
  for (int a = 0; a < 9; ++a) {
    const float s0 = s[a], s1 = s[9 + a];
    const float m = fmaxf(s0, s1);
    const float e0 = expf(s0 - m), e1 = expf(s1 - m);
    const float score = e1 / (e0 + e1);
    const float d0 = d[a * 4 + 0], d1 = d[a * 4 + 1];
    const float d2 = d[a * 4 + 2], d3 = d[a * 4 + 3];
    const float ax1 = A9c[a][0] + sx, ay1 = A9c[a][1] + sy;
    const float ax2 = A9c[a][2] + sx, ay2 = A9c[a][3] + sy;
    const float aw = ax2 - ax1 + 1.f, ah = ay2 - ay1 + 1.f;
    const float acx = ax1 + 0.5f * aw, acy = ay1 + 0.5f * ah;
    const float pcx = d0 * aw + acx, pcy = d1 * ah + acy;
    const float pw = expf(d2) * aw, ph = expf(d3) * ah;
    const float x1 = fminf(fmaxf(pcx - 0.5f * pw, 0.f), imw - 1.f);
    const float y1 = fminf(fmaxf(pcy - 0.5f * ph, 0.f), imh - 1.f);
    const float x2 = fminf(fmaxf(pcx + 0.5f * pw, 0.f), imw - 1.f);
    const float y2 = fminf(fmaxf(pcy + 0.5f * ph, 0.f), imh - 1.f);
    const int n = pos * 9 + a;
    *(float4*)&boxes[((size_t)b * NANCH + n) * 4] = make_float4(x1, y1, x2, y2);
    const unsigned key = __float_as_uint(score);
    skeys[(size_t)b * NANCH + n] = key;
    atomicAdd(&hl[key >> 20], 1u);
  }
  __syncthreads();
  #pragma unroll
  for (int i = 0; i < 16; ++i) {
    unsigned c = hl[tid + i * 256];
    if (c) atomicAdd(&hist[b * 4096 + tid + i * 256], c);
  }
}

// ---------------- fused threshold select + compact (one block per batch, 512 thr) ------
__global__ __launch_bounds__(512) void select_k(
    const unsigned* __restrict__ skeys, const unsigned* __restrict__ hist,
    unsigned* __restrict__ misc, unsigned* __restrict__ ckey,
    unsigned* __restrict__ cidx) {
  const int b = blockIdx.x;
  const int tid = threadIdx.x;
  __shared__ unsigned csum[256];
  __shared__ unsigned hl2[256];
  __shared__ unsigned s_t1, s_cumAbove, s_T2, s_cnt;
  const unsigned* h = hist + b * 4096;
  if (tid < 256) {
    unsigned s = 0;
    #pragma unroll
    for (int i = 0; i < 16; ++i) s += h[tid * 16 + i];
    csum[tid] = s;
    hl2[tid] = 0u;
  }
  __syncthreads();
  if (tid == 0) {
    unsigned cum = 0; int chunk = 0;
    for (int c = 255; c >= 0; --c) {
      if (cum + csum[c] >= (unsigned)PRE_TOPN) { chunk = c; break; }
      cum += csum[c];
    }
    unsigned t1 = chunk * 16, cumAbove = cum;
    for (int i = 15; i >= 0; --i) {
      unsigned cnt = h[chunk * 16 + i];
      if (cum + cnt >= (unsigned)PRE_TOPN) { t1 = chunk * 16 + i; cumAbove = cum; break; }
      cum += cnt;
    }
    s_t1 = t1; s_cumAbove = cumAbove; s_cnt = 0u;
  }
  __syncthreads();
  const unsigned t1 = s_t1;
  const unsigned* sk = skeys + (size_t)b * NANCH;
  for (int t = tid; t < NANCH; t += 512) {
    unsigned key = sk[t];
    if ((key >> 20) == t1) atomicAdd(&hl2[(key >> 12) & 255u], 1u);
  }
  __syncthreads();
  if (tid == 0) {
    unsigned cum = s_cumAbove;
    unsigned T2 = t1 << 20;
    for (int ss = 255; ss >= 0; --ss) {
      unsigned c = hl2[ss];
      if (cum + c >= (unsigned)PRE_TOPN) { T2 = (t1 << 20) | ((unsigned)ss << 12); break; }
      cum += c;
    }
    s_T2 = T2;
  }
  __syncthreads();
  const unsigned T2 = s_T2;
  const int lane = tid & 63;
  for (int t = tid; t < NANCH; t += 512) {
    unsigned key = sk[t];
    bool pred = key >= T2;
    unsigned long long mb = __ballot(pred);
    unsigned base = 0;
    if (lane == 0) base = atomicAdd(&s_cnt, (unsigned)__popcll(mb));
    base = (unsigned)__shfl((int)base, 0, 64);
    if (pred) {
      unsigned pp = base + (unsigned)__popcll(mb & ((1ull << lane) - 1ull));
      if (pp < (unsigned)CAND_CAP) {
        ckey[(size_t)b * CAND_CAP + pp] = key;
        cidx[(size_t)b * CAND_CAP + pp] = (unsigned)t;
      }
    }
  }
  __syncthreads();
  if (tid == 0) misc[12 + b] = s_cnt;
}

// ---------------- exact rank sort of candidates (desc score, asc index) ----------------
__global__ __launch_bounds__(256) void rank_scatter_k(
    const unsigned* __restrict__ ckey, const unsigned* __restrict__ cidx,
    const unsigned* __restrict__ misc, const float* __restrict__ boxes,
    float* __restrict__ sbox) {
  const int b = blockIdx.y;
  const int K = min((int)misc[12 + b], CAND_CAP);
  if (blockIdx.x * 256 >= (unsigned)K) return;   // inactive block: nothing to write
  const int i = blockIdx.x * 256 + threadIdx.x;
  unsigned mykey = 0, myidx = 0;
  const bool active = i < K;
  if (active) {
    mykey = ckey[(size_t)b * CAND_CAP + i];
    myidx = cidx[(size_t)b * CAND_CAP + i];
  }
  int rank = 0;
  __shared__ unsigned skey[1024];
  __shared__ unsigned sidx[1024];
  for (int c0 = 0; c0 < K; c0 += 1024) {
    int n = min(1024, K - c0);
    __syncthreads();
    for (int e = threadIdx.x; e < n; e += 256) {
      skey[e] = ckey[(size_t)b * CAND_CAP + c0 + e];
      sidx[e] = cidx[(size_t)b * CAND_CAP + c0 + e];
    }
    __syncthreads();
    if (active) {
      for (int j = 0; j < n; ++j) {
        unsigned kj = skey[j];
        rank += (kj > mykey) || (kj == mykey && sidx[j] < myidx);
      }
    }
  }
  if (active && rank < PRE_TOPN) {
    float4 bx = *(const float4*)&boxes[((size_t)b * NANCH + myidx) * 4];
    *(float4*)&sbox[((size_t)b * PRE_TOPN + rank) * 4] = bx;
  }
}

// ---------------- fused greedy NMS: tile-sequential, no bit-matrix ----------------
__global__ __launch_bounds__(256) void nms_fused_k(const float* __restrict__ sbox,
                                                   float* __restrict__ out) {
  __shared__ float4 tb[64];                 // current tile's boxes
  __shared__ float4 pk[POST_TOPN];          // picked boxes
  __shared__ unsigned long long supw[4];    // per-wave suppression ballots
  __shared__ int s_np;
  const int b = blockIdx.x;
  const int tid = threadIdx.x;
  const int wv = tid >> 6, lane = tid & 63;
  const float* S = sbox + (size_t)b * PRE_TOPN * 4;
  float* O = out + (size_t)b * POST_TOPN * 5;
  if (tid == 0) s_np = 0;
  int np = 0;

  for (int t = 0; t < (PRE_TOPN + 63) / 64; ++t) {
    __syncthreads();                        // prev phase-2 done (pk, s_np final)
    np = s_np;
    if (np >= POST_TOPN) break;
    const int nt = min(64, PRE_TOPN - t * 64);
    if (tid < 64 && tid < nt) tb[tid] = *(const float4*)&S[(size_t)(t * 64 + tid) * 4];
    __syncthreads();                        // tb staged
    // ---- phase 1: suppression of tile boxes by existing picks ----
    const float4 q = tb[lane < nt ? lane : 0];
    const float qarea = (q.z - q.x + 1.f) * (q.w - q.y + 1.f);
    bool sup = false;
    for (int p = wv; p < np; p += 4) {
      const float4 pb = pk[p];
      const float pa = (pb.z - pb.x + 1.f) * (pb.w - pb.y + 1.f);
      const float xx1 = fmaxf(pb.x, q.x), yy1 = fmaxf(pb.y, q.y);
      const float xx2 = fminf(pb.z, q.z), yy2 = fminf(pb.w, q.w);
      const float inter = fmaxf(xx2 - xx1 + 1.f, 0.f) * fmaxf(yy2 - yy1 + 1.f, 0.f);
      const float iou = inter / (pa + qarea - inter);
      sup = sup || (iou > 0.7f);
    }
    unsigned long long bal = __ballot(sup);
    if (lane == 0) supw[wv] = bal;
    __syncthreads();
    // ---- phase 2: wave 0 resolves intra-tile picks serially ----
    if (wv == 0) {
      const unsigned long long validm = (nt == 64) ? ~0ull : ((1ull << nt) - 1ull);
      unsigned long long remaining = validm & ~(supw[0] | supw[1] | supw[2] | supw[3]);
      while (remaining && np < POST_TOPN) {
        const int jj = __ffsll((long long)remaining) - 1;
        const float4 pb = tb[jj];
        if (lane == 0) {
          pk[np] = pb;
          O[np * 5 + 0] = (float)b;
          O[np * 5 + 1] = pb.x; O[np * 5 + 2] = pb.y;
          O[np * 5 + 3] = pb.z; O[np * 5 + 4] = pb.w;
        }
        const float pa = (pb.z - pb.x + 1.f) * (pb.w - pb.y + 1.f);
        const float xx1 = fmaxf(pb.x, q.x), yy1 = fmaxf(pb.y, q.y);
        const float xx2 = fminf(pb.z, q.z), yy2 = fminf(pb.w, q.w);
        const float inter = fmaxf(xx2 - xx1 + 1.f, 0.f) * fmaxf(yy2 - yy1 + 1.f, 0.f);
        const float iou = inter / (pa + qarea - inter);
        remaining &= ~__ballot(iou > 0.7f);   // self IoU = 1 clears bit jj
        ++np;
      }
      if (lane == 0) s_np = np;
    }
  }
  __syncthreads();
  np = s_np;
  for (int e = tid; e < (POST_TOPN - np) * 5; e += 256) {
    int r = np + e / 5; int c = e - (e / 5) * 5;
    O[r * 5 + c] = (c == 0) ? (float)b : 0.f;
  }
}

// ---------------- launch ----------------
extern "C" void kernel_launch(void* const* d_in, const int* in_sizes, int n_in,
                              void* d_out, int out_size, void* d_ws, size_t ws_size,
                              hipStream_t stream) {
  const float* base_feat = (const float*)d_in[0];
  const float* im_info   = (const float*)d_in[1];
  const float* W_conv    = (const float*)d_in[4];
  const float* b_conv    = (const float*)d_in[5];
  const float* W_cls     = (const float*)d_in[6];
  const float* b_cls     = (const float*)d_in[7];
  const float* W_bbox    = (const float*)d_in[8];
  const float* b_bbox    = (const float*)d_in[9];
  float* out = (float*)d_out;
  char* ws = (char*)d_ws;

  short*    Wb    = (short*)(ws + OFF_WB);
  float*    It    = (float*)(ws + OFF_IT);
  float*    conv  = (float*)(ws + OFF_CONV);
  float*    head  = (float*)(ws + OFF_HEAD);   // overlays Wb (dead after conv)
  unsigned* skeys = (unsigned*)(ws + OFF_SKEY);
  float*    boxes = (float*)(ws + OFF_BOX);
  unsigned* hist  = (unsigned*)(ws + OFF_HIST);
  unsigned* misc  = (unsigned*)(ws + OFF_MISC);
  unsigned* ckey  = (unsigned*)(ws + OFF_CKEY);
  unsigned* cidx  = (unsigned*)(ws + OFF_CIDX);
  float*    sbox  = (float*)(ws + OFF_SBOX);

  hipMemsetAsync(ws + OFF_HIST, 0, 65536 + 256, stream);

  prep_k<<<9216 + 2048, 256, 0, stream>>>(W_conv, Wb, base_feat, It);
  conv_mfma_k<<<dim3(32, 4, 4), 256, 0, stream>>>(It, Wb, b_conv, conv);
  head_mfma_k<<<dim3(64, 4), 256, 0, stream>>>(conv, W_cls, b_cls, W_bbox, b_bbox, head);
  decode_k<<<64, 256, 0, stream>>>(head, im_info, boxes, skeys, hist);
  select_k<<<4, 512, 0, stream>>>(skeys, hist, misc, ckey, cidx);
  rank_scatter_k<<<dim3(CAND_CAP / 256, 4), 256, 0, stream>>>(ckey, cidx, misc, boxes, sbox);
  nms_fused_k<<<4, 256, 0, stream>>>(sbox, out);
}